// Round 1
// baseline (387.931 us; speedup 1.0000x reference)
//
#include <hip/hip_runtime.h>
#include <hip/hip_bf16.h>

// RGCN 2-layer forward. dst-major, rel-grouped counting sort with ONE atomic
// per edge — but atomics are now XCD-LOCAL: each workgroup counts into its
// physical XCD's private copy (HW_REG_XCC_ID) with workgroup-scope atomicAdd,
// which executes in the local TCC instead of the device coherence point
// (device-scope atomicAdd = memory-side RMW, measured 53 MB WRITE_SIZE / 67 us).
// A merge pass computes cross-copy prefixes + totals; segbase bakes
// offs[d]+relstart+cnt into one word so scatter is two 4B gathers per edge.
// l1/l2 are pure gather (zero accumulation atomics), unchanged.

constexpr int Nn = 50000;
constexpr int Hh = 16;
constexpr int Rr = 32;
constexpr int Cc = 8;
constexpr int Ee = 1600000;
constexpr int NBLK = (Nn + 255) / 256;   // 196
constexpr int NXCD = 8;
constexpr int CW = Nn * 8;               // 400000 u32 words per copy (u8 x 32 rels)

__device__ __forceinline__ float b2f(__hip_bfloat16 v) { return __bfloat162float(v); }

// --- 0. dtype sniff (bf16 vs fp32 delivery) -----------------------------------
__global__ void sniff_kernel(const unsigned short* __restrict__ w, int* __restrict__ flag) {
    if (blockIdx.x == 0 && threadIdx.x == 0) {
        int hits = 0;
        for (int i = 0; i < 64; ++i) {
            unsigned short u = w[2 * i];
            int e = (u >> 7) & 0xFF;
            if (e >= 100 && e <= 130) ++hits;
        }
        *flag = (hits >= 32) ? 1 : 0;   // 1 = bf16, 0 = fp32
    }
}

// --- 1. XCD-local count per (rel,dst); atomic return = rank in (seg,xcd) ------
// copies[p][d*8 + (r>>2)] holds 4 u8 count fields (r&3). Workgroup-scope
// atomic executes at the local TCC; all updaters of copy p share that L2
// (same physical XCD), so atomicity holds without cross-XCD coherence.
__global__ void count_kernel(const int* __restrict__ dst, const int* __restrict__ et,
                             unsigned* __restrict__ copies,
                             unsigned short* __restrict__ rank16) {
    int e = blockIdx.x * blockDim.x + threadIdx.x;
    if (e >= Ee) return;
    unsigned xcc;
    asm volatile("s_getreg_b32 %0, hwreg(HW_REG_XCC_ID)" : "=s"(xcc));
    int p = (int)(xcc & 7u);
    int d = dst[e], r = et[e];
    int word = p * CW + d * 8 + (r >> 2);
    int sh = 8 * (r & 3);
    unsigned old = __hip_atomic_fetch_add(&copies[word], 1u << sh,
                                          __ATOMIC_RELAXED, __HIP_MEMORY_SCOPE_WORKGROUP);
    // rank (<=255 by u8 field) in low 13 bits, xcd in top 3
    rank16[e] = (unsigned short)(((old >> sh) & 0xFFu) | ((unsigned)p << 13));
}

// --- 1b. merge copies: totals (packed u16, cnt2pk layout) + in-place exclusive
//         cross-copy prefix (u8 fields; prefix <= total <= ~10 for this input)
__global__ __launch_bounds__(256) void merge_kernel(unsigned* __restrict__ copies,
                                                    uint2* __restrict__ totals2) {
    int i = blockIdx.x * 256 + threadIdx.x;     // word over [Nn*8)
    if (i >= CW) return;
    unsigned r0 = 0, r1 = 0, r2 = 0, r3 = 0;
    unsigned pw[NXCD];
#pragma unroll
    for (int p = 0; p < NXCD; ++p) {
        unsigned c = copies[p * CW + i];
        pw[p] = r0 | (r1 << 8) | (r2 << 16) | (r3 << 24);
        r0 += c & 0xFFu; r1 += (c >> 8) & 0xFFu; r2 += (c >> 16) & 0xFFu; r3 += c >> 24;
    }
#pragma unroll
    for (int p = 0; p < NXCD; ++p) copies[p * CW + i] = pw[p];
    // totals word pair at u32 index 2*i == d*16 + 2*w8  (cnt2pk halfword layout)
    totals2[i] = make_uint2(r0 | (r1 << 16), r2 | (r3 << 16));
}

// --- 2a. per-dst degree (sum of 16 packed words) + block exclusive scan -------
__global__ __launch_bounds__(256) void scan1_kernel(const uint4* __restrict__ cnt2pk4,
                                                    int* __restrict__ offs,
                                                    int* __restrict__ bsum) {
    __shared__ int lsum[4];
    int tid = threadIdx.x, lane = tid & 63, w = tid >> 6;
    int d = blockIdx.x * 256 + tid;
    int v = 0;
    if (d < Nn) {
        const uint4* p = cnt2pk4 + (size_t)d * 4;
        uint4 a = p[0], b = p[1], c = p[2], q = p[3];
        unsigned s = a.x + a.y + a.z + a.w + b.x + b.y + b.z + b.w
                   + c.x + c.y + c.z + c.w + q.x + q.y + q.z + q.w;
        v = (int)((s & 0xFFFFu) + (s >> 16));   // halves can't overflow: deg<=65535
    }
    int s = v;
#pragma unroll
    for (int o = 1; o < 64; o <<= 1) { int t = __shfl_up(s, o, 64); if (lane >= o) s += t; }
    if (lane == 63) lsum[w] = s;
    __syncthreads();
    int base = 0;
    for (int j = 0; j < w; ++j) base += lsum[j];
    int excl = base + s - v;
    if (d < Nn) offs[d] = excl;
    if (tid == 255) bsum[blockIdx.x] = excl + v;
}

// --- 2b. scan block sums (NBLK<=256); grand total -> offs[Nn] -----------------
__global__ __launch_bounds__(256) void scan2_kernel(const int* __restrict__ bsum,
                                                    int* __restrict__ carry,
                                                    int* __restrict__ offs) {
    __shared__ int lsum[4];
    int tid = threadIdx.x, lane = tid & 63, w = tid >> 6;
    int v = (tid < NBLK) ? bsum[tid] : 0;
    int s = v;
#pragma unroll
    for (int o = 1; o < 64; o <<= 1) { int t = __shfl_up(s, o, 64); if (lane >= o) s += t; }
    if (lane == 63) lsum[w] = s;
    __syncthreads();
    int base = 0;
    for (int j = 0; j < w; ++j) base += lsum[j];
    int excl = base + s - v;
    if (tid < NBLK) carry[tid] = excl;
    if (tid == 255) offs[Nn] = excl;
}

// --- 2c. add carries ----------------------------------------------------------
__global__ void scan3_kernel(int* __restrict__ offs, const int* __restrict__ carry) {
    int i = blockIdx.x * 256 + threadIdx.x;
    if (i < Nn) offs[i] += carry[blockIdx.x];
}

// --- 2d. segbase[d*32+r] = (offs[d]+relstart) | min(cnt,2047)<<21 -------------
// one lane per (d,r): 32-lane shuffle scan gives exclusive relstart.
__global__ __launch_bounds__(256) void segbase_kernel(const int* __restrict__ offs,
                                                      const unsigned* __restrict__ totals,
                                                      unsigned* __restrict__ segbase) {
    int tid = threadIdx.x, lane = tid & 63;
    int r = lane & 31, half = lane >> 5, wv = tid >> 6;
    int d = blockIdx.x * 8 + wv * 2 + half;          // 6250 * 8 == Nn
    unsigned tw = totals[d * 16 + (r >> 1)];
    int cnt = (r & 1) ? (int)(tw >> 16) : (int)(tw & 0xFFFFu);
    int s = cnt;
#pragma unroll
    for (int o = 1; o < 32; o <<= 1) { int t = __shfl_up(s, o, 32); if (r >= o) s += t; }
    int base = offs[d] + (s - cnt);                  // base <= E < 2^21
    unsigned cc = (unsigned)(cnt < 2047 ? cnt : 2047);
    segbase[d * 32 + r] = (unsigned)base | (cc << 21);
}

// --- 3. atomic-free scatter; pos = segbase + copyprefix + rank ----------------
__global__ void scatter_kernel(const int* __restrict__ src, const int* __restrict__ dst,
                               const int* __restrict__ et,
                               const unsigned* __restrict__ segbase,
                               const unsigned* __restrict__ copies,
                               const unsigned short* __restrict__ rank16,
                               unsigned* __restrict__ sorted) {
    int e = blockIdx.x * blockDim.x + threadIdx.x;
    if (e >= Ee) return;
    int d = dst[e], r = et[e];
    unsigned rr = rank16[e];
    int p = (int)(rr >> 13), rank = (int)(rr & 0x1FFFu);
    unsigned sb = segbase[d * 32 + r];
    unsigned cw = copies[p * CW + d * 8 + (r >> 2)];
    int cpre = (int)((cw >> (8 * (r & 3))) & 0xFFu);
    int pos = (int)(sb & 0x1FFFFFu) + cpre + rank;
    sorted[pos] = (unsigned)src[e] | ((unsigned)r << 16) | ((sb >> 21) << 21);
}

// --- 4. layer 1: one wave per dst, 8 edges x 8 lanes (bf16x2/float2) ----------
__global__ __launch_bounds__(256) void l1_kernel(const unsigned* __restrict__ sorted,
                                                 const int* __restrict__ offs,
                                                 const void* __restrict__ w1,
                                                 const void* __restrict__ root1,
                                                 const void* __restrict__ b1,
                                                 const int* __restrict__ flag,
                                                 float* __restrict__ x) {
    int tid = threadIdx.x, w = tid >> 6, lane = tid & 63;
    int ep = lane >> 3, hp = lane & 7;
    int isbf = *flag;
    int d = blockIdx.x * 4 + w;                  // 12500*4 == Nn
    int off = offs[d], deg = offs[d + 1] - off;
    float a0 = 0.0f, a1 = 0.0f;
    if (isbf) {
#pragma unroll 2
        for (int i = ep; i < deg; i += 8) {
            unsigned p = sorted[off + i];
            int cnt = p >> 21, rel = (p >> 16) & 31, s = p & 0xFFFF;
            float inv = __builtin_amdgcn_rcpf((float)cnt);
            __hip_bfloat162 v = ((const __hip_bfloat162*)w1)[((size_t)rel * Nn + s) * 8 + hp];
            a0 += inv * __low2float(v); a1 += inv * __high2float(v);
        }
    } else {
#pragma unroll 2
        for (int i = ep; i < deg; i += 8) {
            unsigned p = sorted[off + i];
            int cnt = p >> 21, rel = (p >> 16) & 31, s = p & 0xFFFF;
            float inv = __builtin_amdgcn_rcpf((float)cnt);
            float2 v = ((const float2*)w1)[((size_t)rel * Nn + s) * 8 + hp];
            a0 += inv * v.x; a1 += inv * v.y;
        }
    }
#pragma unroll
    for (int o = 8; o < 64; o <<= 1) {
        a0 += __shfl_xor(a0, o, 64);
        a1 += __shfl_xor(a1, o, 64);
    }
    if (ep == 0) {
        float r0, r1v, bb0, bb1;
        if (isbf) {
            r0  = b2f(((const __hip_bfloat16*)root1)[d * Hh + hp * 2]);
            r1v = b2f(((const __hip_bfloat16*)root1)[d * Hh + hp * 2 + 1]);
            bb0 = b2f(((const __hip_bfloat16*)b1)[hp * 2]);
            bb1 = b2f(((const __hip_bfloat16*)b1)[hp * 2 + 1]);
        } else {
            r0  = ((const float*)root1)[d * Hh + hp * 2];
            r1v = ((const float*)root1)[d * Hh + hp * 2 + 1];
            bb0 = ((const float*)b1)[hp * 2];
            bb1 = ((const float*)b1)[hp * 2 + 1];
        }
        float v0 = a0 + r0 + bb0, v1 = a1 + r1v + bb1;
        *(float2*)(x + (size_t)d * Hh + hp * 2) =
            make_float2(v0 > 0.f ? v0 : 0.f, v1 > 0.f ? v1 : 0.f);
    }
}

// --- 5. layer 2 + epilogue: one wave per dst, 8 edges x 8 classes, reg dots ---
__global__ __launch_bounds__(256) void l2_kernel(const unsigned* __restrict__ sorted,
                                                 const int* __restrict__ offs,
                                                 const float* __restrict__ x,
                                                 const void* __restrict__ w2,
                                                 const void* __restrict__ root2,
                                                 const void* __restrict__ b2v,
                                                 const int* __restrict__ flag,
                                                 void* __restrict__ out) {
    __shared__ float w2s[32 * 132];   // [rel]*132 + c*16 + h  (pad 132: ~2-way banks)
    __shared__ float rsh[128];        // root2 [h*8+c]
    __shared__ float b2sh[8];
    int tid = threadIdx.x, w = tid >> 6, lane = tid & 63;
    int isbf = *flag;
    {
        int r = tid >> 3, cc = tid & 7;
        if (isbf) {
            const __hip_bfloat16* W = (const __hip_bfloat16*)w2 + r * 128 + cc;
#pragma unroll
            for (int h = 0; h < 16; ++h) w2s[r * 132 + cc * 16 + h] = b2f(W[h * 8]);
        } else {
            const float* W = (const float*)w2 + r * 128 + cc;
#pragma unroll
            for (int h = 0; h < 16; ++h) w2s[r * 132 + cc * 16 + h] = W[h * 8];
        }
    }
    if (tid < 128) rsh[tid] = isbf ? b2f(((const __hip_bfloat16*)root2)[tid])
                                   : ((const float*)root2)[tid];
    if (tid < 8)   b2sh[tid] = isbf ? b2f(((const __hip_bfloat16*)b2v)[tid])
                                    : ((const float*)b2v)[tid];
    __syncthreads();
    int ep = lane >> 3, c = lane & 7;
    int d = blockIdx.x * 4 + w;
    int off = offs[d], deg = offs[d + 1] - off;
    float acc = 0.0f;
    for (int i0 = 0; i0 < deg; i0 += 8) {
        int i = i0 + ep;
        if (i < deg) {
            unsigned p = sorted[off + i];
            int cnt = p >> 21, rel = (p >> 16) & 31, s = p & 0xFFFF;
            float inv = __builtin_amdgcn_rcpf((float)cnt);
            const float4* xr = (const float4*)(x + (size_t)s * Hh);
            float4 x0 = xr[0], x1 = xr[1], x2 = xr[2], x3 = xr[3];
            const float4* wv = (const float4*)(w2s + rel * 132 + c * 16);
            float4 w0 = wv[0], w1v = wv[1], w2v = wv[2], w3 = wv[3];
            float dot = x0.x*w0.x + x0.y*w0.y + x0.z*w0.z + x0.w*w0.w
                      + x1.x*w1v.x + x1.y*w1v.y + x1.z*w1v.z + x1.w*w1v.w
                      + x2.x*w2v.x + x2.y*w2v.y + x2.z*w2v.z + x2.w*w2v.w
                      + x3.x*w3.x + x3.y*w3.y + x3.z*w3.z + x3.w*w3.w;
            acc += inv * dot;
        }
    }
    acc += __shfl_xor(acc, 8, 64);
    acc += __shfl_xor(acc, 16, 64);
    acc += __shfl_xor(acc, 32, 64);
    if (ep == 0) {
        const float4* xr = (const float4*)(x + (size_t)d * Hh);
        float4 x0 = xr[0], x1 = xr[1], x2 = xr[2], x3 = xr[3];
        float xv[16] = {x0.x,x0.y,x0.z,x0.w, x1.x,x1.y,x1.z,x1.w,
                        x2.x,x2.y,x2.z,x2.w, x3.x,x3.y,x3.z,x3.w};
        float v = acc + b2sh[c];
#pragma unroll
        for (int h = 0; h < 16; ++h) v += xv[h] * rsh[h * 8 + c];
        float m = v;
#pragma unroll
        for (int o = 1; o < 8; o <<= 1) m = fmaxf(m, __shfl_xor(m, o, 8));
        float ssum = __expf(v - m);
#pragma unroll
        for (int o = 1; o < 8; o <<= 1) ssum += __shfl_xor(ssum, o, 8);
        float res = v - m - __logf(ssum);
        if (isbf) ((__hip_bfloat16*)out)[(size_t)d * Cc + c] = __float2bfloat16(res);
        else      ((float*)out)[(size_t)d * Cc + c] = res;
    }
}

extern "C" void kernel_launch(void* const* d_in, const int* in_sizes, int n_in,
                              void* d_out, int out_size, void* d_ws, size_t ws_size,
                              hipStream_t stream) {
    const int* edge_index = (const int*)d_in[0];     // [2, E]
    const int* src = edge_index;
    const int* dst = edge_index + Ee;
    const int* et  = (const int*)d_in[1];            // [E]
    const void* w1    = d_in[2];  // [R,N,H]
    const void* root1 = d_in[3];  // [N,H]
    const void* b1    = d_in[4];  // [H]
    const void* w2    = d_in[5];  // [R,H,C]
    const void* root2 = d_in[6];  // [H,C]
    const void* b2    = d_in[7];  // [C]

    // ws (u32 words, ~32.3 MB total):
    // copies[8][CW] (x[800000] overlays after scatter) | totals[800000] |
    // rank16[800000 w] | offs[Nn+4] | bsum[256] | carry[256] |
    // segbase[1600000] | sorted[Ee] | flag[1]
    unsigned* copies = (unsigned*)d_ws;
    unsigned* totals = copies + (size_t)NXCD * CW;
    unsigned short* rank16 = (unsigned short*)(totals + (size_t)Nn * 16);
    int* offs  = (int*)(rank16 + Ee);
    int* bsum  = offs + Nn + 4;
    int* carry = bsum + 256;
    unsigned* segbase = (unsigned*)(carry + 256);
    unsigned* sorted  = segbase + (size_t)Nn * 32;
    int* flag  = (int*)(sorted + Ee);
    float* x   = (float*)copies;     // overlay: copies dead after scatter

    hipMemsetAsync(copies, 0, (size_t)NXCD * CW * sizeof(unsigned), stream);

    sniff_kernel<<<1, 64, 0, stream>>>((const unsigned short*)w1, flag);
    count_kernel<<<(Ee + 255) / 256, 256, 0, stream>>>(dst, et, copies, rank16);
    merge_kernel<<<(CW + 255) / 256, 256, 0, stream>>>(copies, (uint2*)totals);
    scan1_kernel<<<NBLK, 256, 0, stream>>>((const uint4*)totals, offs, bsum);
    scan2_kernel<<<1, 256, 0, stream>>>(bsum, carry, offs);
    scan3_kernel<<<NBLK, 256, 0, stream>>>(offs, carry);
    segbase_kernel<<<Nn / 8, 256, 0, stream>>>(offs, totals, segbase);
    scatter_kernel<<<(Ee + 255) / 256, 256, 0, stream>>>(src, dst, et, segbase,
                                                         copies, rank16, sorted);
    l1_kernel<<<Nn / 4, 256, 0, stream>>>(sorted, offs, w1, root1, b1, flag, x);
    l2_kernel<<<Nn / 4, 256, 0, stream>>>(sorted, offs, x, w2, root2, b2, flag, d_out);
}

// Round 3
// 383.412 us; speedup vs baseline: 1.0118x; 1.0118x over previous
//
#include <hip/hip_runtime.h>
#include <hip/hip_bf16.h>

// RGCN 2-layer forward. dst-major, rel-grouped counting sort with ONE atomic
// per edge. Round-2 finding: the atomic executes memory-side (32B sector
// write-through, 53MB WRITE_SIZE) REGARDLESS of scope — count/scatter are
// LATENCY-bound with MLP=1 per thread. Fix: 8-edge ILP batching per thread
// (block-strided, coalesced): issue 8 independent atomics/gathers before the
// first dependent use. XCD-copy structure kept (merge gives cross-copy
// prefixes; segbase bakes offs[d]+relstart+cnt into one word so scatter is
// two 4B gathers/edge). l1/l2 pure gather, unchanged.
// (Round-3 resubmit: round-2 bench was an infra failure, no counter data.)

constexpr int Nn = 50000;
constexpr int Hh = 16;
constexpr int Rr = 32;
constexpr int Cc = 8;
constexpr int Ee = 1600000;
constexpr int NBLK = (Nn + 255) / 256;   // 196
constexpr int NXCD = 8;
constexpr int CW = Nn * 8;               // 400000 u32 words per copy (u8 x 32 rels)
constexpr int KC = 8;                    // edges per thread, count
constexpr int KS = 8;                    // edges per thread, scatter

__device__ __forceinline__ float b2f(__hip_bfloat16 v) { return __bfloat162float(v); }

// --- 0. dtype sniff (bf16 vs fp32 delivery) -----------------------------------
__global__ void sniff_kernel(const unsigned short* __restrict__ w, int* __restrict__ flag) {
    if (blockIdx.x == 0 && threadIdx.x == 0) {
        int hits = 0;
        for (int i = 0; i < 64; ++i) {
            unsigned short u = w[2 * i];
            int e = (u >> 7) & 0xFF;
            if (e >= 100 && e <= 130) ++hits;
        }
        *flag = (hits >= 32) ? 1 : 0;   // 1 = bf16, 0 = fp32
    }
}

// --- 1. XCD-local count per (rel,dst); atomic return = rank in (seg,xcd) ------
// 8 edges per thread, block-strided: phase A loads 8 coalesced (d,r) pairs,
// phase B issues 8 independent atomics (all in flight), phase C drains ranks.
__global__ __launch_bounds__(256) void count_kernel(const int* __restrict__ dst,
                                                    const int* __restrict__ et,
                                                    unsigned* __restrict__ copies,
                                                    unsigned short* __restrict__ rank16) {
    unsigned xcc;
    asm volatile("s_getreg_b32 %0, hwreg(HW_REG_XCC_ID)" : "=s"(xcc));
    int p = (int)(xcc & 7u);
    int base = blockIdx.x * (256 * KC) + threadIdx.x;
    int d[KC], r[KC];
#pragma unroll
    for (int k = 0; k < KC; ++k) {
        int e = base + 256 * k;
        if (e < Ee) { d[k] = dst[e]; r[k] = et[e]; } else { d[k] = -1; r[k] = 0; }
    }
    unsigned old[KC];
#pragma unroll
    for (int k = 0; k < KC; ++k) {
        if (d[k] >= 0) {
            int word = p * CW + d[k] * 8 + (r[k] >> 2);
            old[k] = __hip_atomic_fetch_add(&copies[word], 1u << (8 * (r[k] & 3)),
                                            __ATOMIC_RELAXED, __HIP_MEMORY_SCOPE_WORKGROUP);
        }
    }
#pragma unroll
    for (int k = 0; k < KC; ++k) {
        if (d[k] >= 0) {
            rank16[base + 256 * k] =
                (unsigned short)(((old[k] >> (8 * (r[k] & 3))) & 0xFFu) | ((unsigned)p << 13));
        }
    }
}

// --- 1b. merge copies: totals (packed u16, cnt2pk layout) + in-place exclusive
//         cross-copy prefix (u8 fields; prefix <= total <= ~10 for this input)
__global__ __launch_bounds__(256) void merge_kernel(unsigned* __restrict__ copies,
                                                    uint2* __restrict__ totals2) {
    int i = blockIdx.x * 256 + threadIdx.x;     // word over [Nn*8)
    if (i >= CW) return;
    unsigned r0 = 0, r1 = 0, r2 = 0, r3 = 0;
    unsigned pw[NXCD];
#pragma unroll
    for (int p = 0; p < NXCD; ++p) {
        unsigned c = copies[p * CW + i];
        pw[p] = r0 | (r1 << 8) | (r2 << 16) | (r3 << 24);
        r0 += c & 0xFFu; r1 += (c >> 8) & 0xFFu; r2 += (c >> 16) & 0xFFu; r3 += c >> 24;
    }
#pragma unroll
    for (int p = 0; p < NXCD; ++p) copies[p * CW + i] = pw[p];
    // totals word pair at u32 index 2*i == d*16 + 2*w8  (cnt2pk halfword layout)
    totals2[i] = make_uint2(r0 | (r1 << 16), r2 | (r3 << 16));
}

// --- 2a. per-dst degree (sum of 16 packed words) + block exclusive scan -------
__global__ __launch_bounds__(256) void scan1_kernel(const uint4* __restrict__ cnt2pk4,
                                                    int* __restrict__ offs,
                                                    int* __restrict__ bsum) {
    __shared__ int lsum[4];
    int tid = threadIdx.x, lane = tid & 63, w = tid >> 6;
    int d = blockIdx.x * 256 + tid;
    int v = 0;
    if (d < Nn) {
        const uint4* p = cnt2pk4 + (size_t)d * 4;
        uint4 a = p[0], b = p[1], c = p[2], q = p[3];
        unsigned s = a.x + a.y + a.z + a.w + b.x + b.y + b.z + b.w
                   + c.x + c.y + c.z + c.w + q.x + q.y + q.z + q.w;
        v = (int)((s & 0xFFFFu) + (s >> 16));   // halves can't overflow: deg<=65535
    }
    int s = v;
#pragma unroll
    for (int o = 1; o < 64; o <<= 1) { int t = __shfl_up(s, o, 64); if (lane >= o) s += t; }
    if (lane == 63) lsum[w] = s;
    __syncthreads();
    int base = 0;
    for (int j = 0; j < w; ++j) base += lsum[j];
    int excl = base + s - v;
    if (d < Nn) offs[d] = excl;
    if (tid == 255) bsum[blockIdx.x] = excl + v;
}

// --- 2b. scan block sums (NBLK<=256); grand total -> offs[Nn] -----------------
__global__ __launch_bounds__(256) void scan2_kernel(const int* __restrict__ bsum,
                                                    int* __restrict__ carry,
                                                    int* __restrict__ offs) {
    __shared__ int lsum[4];
    int tid = threadIdx.x, lane = tid & 63, w = tid >> 6;
    int v = (tid < NBLK) ? bsum[tid] : 0;
    int s = v;
#pragma unroll
    for (int o = 1; o < 64; o <<= 1) { int t = __shfl_up(s, o, 64); if (lane >= o) s += t; }
    if (lane == 63) lsum[w] = s;
    __syncthreads();
    int base = 0;
    for (int j = 0; j < w; ++j) base += lsum[j];
    int excl = base + s - v;
    if (tid < NBLK) carry[tid] = excl;
    if (tid == 255) offs[Nn] = excl;
}

// --- 2c. add carries ----------------------------------------------------------
__global__ void scan3_kernel(int* __restrict__ offs, const int* __restrict__ carry) {
    int i = blockIdx.x * 256 + threadIdx.x;
    if (i < Nn) offs[i] += carry[blockIdx.x];
}

// --- 2d. segbase[d*32+r] = (offs[d]+relstart) | min(cnt,2047)<<21 -------------
// one lane per (d,r): 32-lane shuffle scan gives exclusive relstart.
__global__ __launch_bounds__(256) void segbase_kernel(const int* __restrict__ offs,
                                                      const unsigned* __restrict__ totals,
                                                      unsigned* __restrict__ segbase) {
    int tid = threadIdx.x, lane = tid & 63;
    int r = lane & 31, half = lane >> 5, wv = tid >> 6;
    int d = blockIdx.x * 8 + wv * 2 + half;          // 6250 * 8 == Nn
    unsigned tw = totals[d * 16 + (r >> 1)];
    int cnt = (r & 1) ? (int)(tw >> 16) : (int)(tw & 0xFFFFu);
    int s = cnt;
#pragma unroll
    for (int o = 1; o < 32; o <<= 1) { int t = __shfl_up(s, o, 32); if (r >= o) s += t; }
    int base = offs[d] + (s - cnt);                  // base <= E < 2^21
    unsigned cc = (unsigned)(cnt < 2047 ? cnt : 2047);
    segbase[d * 32 + r] = (unsigned)base | (cc << 21);
}

// --- 3. atomic-free scatter; pos = segbase + copyprefix + rank ----------------
// 8 edges per thread: phase A coalesced loads, phase B 16 independent gathers
// in flight, phase C stores.
__global__ __launch_bounds__(256) void scatter_kernel(const int* __restrict__ src,
                                                      const int* __restrict__ dst,
                                                      const int* __restrict__ et,
                                                      const unsigned* __restrict__ segbase,
                                                      const unsigned* __restrict__ copies,
                                                      const unsigned short* __restrict__ rank16,
                                                      unsigned* __restrict__ sorted) {
    int base = blockIdx.x * (256 * KS) + threadIdx.x;
    int d[KS], r[KS], s[KS];
    unsigned rr[KS];
#pragma unroll
    for (int k = 0; k < KS; ++k) {
        int e = base + 256 * k;
        if (e < Ee) { d[k] = dst[e]; r[k] = et[e]; s[k] = src[e]; rr[k] = rank16[e]; }
        else { d[k] = -1; r[k] = 0; s[k] = 0; rr[k] = 0; }
    }
    unsigned sb[KS], cw[KS];
#pragma unroll
    for (int k = 0; k < KS; ++k) {
        if (d[k] >= 0) {
            int p = (int)(rr[k] >> 13);
            sb[k] = segbase[d[k] * 32 + r[k]];
            cw[k] = copies[p * CW + d[k] * 8 + (r[k] >> 2)];
        }
    }
#pragma unroll
    for (int k = 0; k < KS; ++k) {
        if (d[k] >= 0) {
            int cpre = (int)((cw[k] >> (8 * (r[k] & 3))) & 0xFFu);
            int pos = (int)(sb[k] & 0x1FFFFFu) + cpre + (int)(rr[k] & 0x1FFFu);
            sorted[pos] = (unsigned)s[k] | ((unsigned)r[k] << 16) | ((sb[k] >> 21) << 21);
        }
    }
}

// --- 4. layer 1: one wave per dst, 8 edges x 8 lanes (bf16x2/float2) ----------
__global__ __launch_bounds__(256) void l1_kernel(const unsigned* __restrict__ sorted,
                                                 const int* __restrict__ offs,
                                                 const void* __restrict__ w1,
                                                 const void* __restrict__ root1,
                                                 const void* __restrict__ b1,
                                                 const int* __restrict__ flag,
                                                 float* __restrict__ x) {
    int tid = threadIdx.x, w = tid >> 6, lane = tid & 63;
    int ep = lane >> 3, hp = lane & 7;
    int isbf = *flag;
    int d = blockIdx.x * 4 + w;                  // 12500*4 == Nn
    int off = offs[d], deg = offs[d + 1] - off;
    float a0 = 0.0f, a1 = 0.0f;
    if (isbf) {
#pragma unroll 2
        for (int i = ep; i < deg; i += 8) {
            unsigned p = sorted[off + i];
            int cnt = p >> 21, rel = (p >> 16) & 31, s = p & 0xFFFF;
            float inv = __builtin_amdgcn_rcpf((float)cnt);
            __hip_bfloat162 v = ((const __hip_bfloat162*)w1)[((size_t)rel * Nn + s) * 8 + hp];
            a0 += inv * __low2float(v); a1 += inv * __high2float(v);
        }
    } else {
#pragma unroll 2
        for (int i = ep; i < deg; i += 8) {
            unsigned p = sorted[off + i];
            int cnt = p >> 21, rel = (p >> 16) & 31, s = p & 0xFFFF;
            float inv = __builtin_amdgcn_rcpf((float)cnt);
            float2 v = ((const float2*)w1)[((size_t)rel * Nn + s) * 8 + hp];
            a0 += inv * v.x; a1 += inv * v.y;
        }
    }
#pragma unroll
    for (int o = 8; o < 64; o <<= 1) {
        a0 += __shfl_xor(a0, o, 64);
        a1 += __shfl_xor(a1, o, 64);
    }
    if (ep == 0) {
        float r0, r1v, bb0, bb1;
        if (isbf) {
            r0  = b2f(((const __hip_bfloat16*)root1)[d * Hh + hp * 2]);
            r1v = b2f(((const __hip_bfloat16*)root1)[d * Hh + hp * 2 + 1]);
            bb0 = b2f(((const __hip_bfloat16*)b1)[hp * 2]);
            bb1 = b2f(((const __hip_bfloat16*)b1)[hp * 2 + 1]);
        } else {
            r0  = ((const float*)root1)[d * Hh + hp * 2];
            r1v = ((const float*)root1)[d * Hh + hp * 2 + 1];
            bb0 = ((const float*)b1)[hp * 2];
            bb1 = ((const float*)b1)[hp * 2 + 1];
        }
        float v0 = a0 + r0 + bb0, v1 = a1 + r1v + bb1;
        *(float2*)(x + (size_t)d * Hh + hp * 2) =
            make_float2(v0 > 0.f ? v0 : 0.f, v1 > 0.f ? v1 : 0.f);
    }
}

// --- 5. layer 2 + epilogue: one wave per dst, 8 edges x 8 classes, reg dots ---
__global__ __launch_bounds__(256) void l2_kernel(const unsigned* __restrict__ sorted,
                                                 const int* __restrict__ offs,
                                                 const float* __restrict__ x,
                                                 const void* __restrict__ w2,
                                                 const void* __restrict__ root2,
                                                 const void* __restrict__ b2v,
                                                 const int* __restrict__ flag,
                                                 void* __restrict__ out) {
    __shared__ float w2s[32 * 132];   // [rel]*132 + c*16 + h  (pad 132: ~2-way banks)
    __shared__ float rsh[128];        // root2 [h*8+c]
    __shared__ float b2sh[8];
    int tid = threadIdx.x, w = tid >> 6, lane = tid & 63;
    int isbf = *flag;
    {
        int r = tid >> 3, cc = tid & 7;
        if (isbf) {
            const __hip_bfloat16* W = (const __hip_bfloat16*)w2 + r * 128 + cc;
#pragma unroll
            for (int h = 0; h < 16; ++h) w2s[r * 132 + cc * 16 + h] = b2f(W[h * 8]);
        } else {
            const float* W = (const float*)w2 + r * 128 + cc;
#pragma unroll
            for (int h = 0; h < 16; ++h) w2s[r * 132 + cc * 16 + h] = W[h * 8];
        }
    }
    if (tid < 128) rsh[tid] = isbf ? b2f(((const __hip_bfloat16*)root2)[tid])
                                   : ((const float*)root2)[tid];
    if (tid < 8)   b2sh[tid] = isbf ? b2f(((const __hip_bfloat16*)b2v)[tid])
                                    : ((const float*)b2v)[tid];
    __syncthreads();
    int ep = lane >> 3, c = lane & 7;
    int d = blockIdx.x * 4 + w;
    int off = offs[d], deg = offs[d + 1] - off;
    float acc = 0.0f;
    for (int i0 = 0; i0 < deg; i0 += 8) {
        int i = i0 + ep;
        if (i < deg) {
            unsigned p = sorted[off + i];
            int cnt = p >> 21, rel = (p >> 16) & 31, s = p & 0xFFFF;
            float inv = __builtin_amdgcn_rcpf((float)cnt);
            const float4* xr = (const float4*)(x + (size_t)s * Hh);
            float4 x0 = xr[0], x1 = xr[1], x2 = xr[2], x3 = xr[3];
            const float4* wv = (const float4*)(w2s + rel * 132 + c * 16);
            float4 w0 = wv[0], w1v = wv[1], w2v = wv[2], w3 = wv[3];
            float dot = x0.x*w0.x + x0.y*w0.y + x0.z*w0.z + x0.w*w0.w
                      + x1.x*w1v.x + x1.y*w1v.y + x1.z*w1v.z + x1.w*w1v.w
                      + x2.x*w2v.x + x2.y*w2v.y + x2.z*w2v.z + x2.w*w2v.w
                      + x3.x*w3.x + x3.y*w3.y + x3.z*w3.z + x3.w*w3.w;
            acc += inv * dot;
        }
    }
    acc += __shfl_xor(acc, 8, 64);
    acc += __shfl_xor(acc, 16, 64);
    acc += __shfl_xor(acc, 32, 64);
    if (ep == 0) {
        const float4* xr = (const float4*)(x + (size_t)d * Hh);
        float4 x0 = xr[0], x1 = xr[1], x2 = xr[2], x3 = xr[3];
        float xv[16] = {x0.x,x0.y,x0.z,x0.w, x1.x,x1.y,x1.z,x1.w,
                        x2.x,x2.y,x2.z,x2.w, x3.x,x3.y,x3.z,x3.w};
        float v = acc + b2sh[c];
#pragma unroll
        for (int h = 0; h < 16; ++h) v += xv[h] * rsh[h * 8 + c];
        float m = v;
#pragma unroll
        for (int o = 1; o < 8; o <<= 1) m = fmaxf(m, __shfl_xor(m, o, 8));
        float ssum = __expf(v - m);
#pragma unroll
        for (int o = 1; o < 8; o <<= 1) ssum += __shfl_xor(ssum, o, 8);
        float res = v - m - __logf(ssum);
        if (isbf) ((__hip_bfloat16*)out)[(size_t)d * Cc + c] = __float2bfloat16(res);
        else      ((float*)out)[(size_t)d * Cc + c] = res;
    }
}

extern "C" void kernel_launch(void* const* d_in, const int* in_sizes, int n_in,
                              void* d_out, int out_size, void* d_ws, size_t ws_size,
                              hipStream_t stream) {
    const int* edge_index = (const int*)d_in[0];     // [2, E]
    const int* src = edge_index;
    const int* dst = edge_index + Ee;
    const int* et  = (const int*)d_in[1];            // [E]
    const void* w1    = d_in[2];  // [R,N,H]
    const void* root1 = d_in[3];  // [N,H]
    const void* b1    = d_in[4];  // [H]
    const void* w2    = d_in[5];  // [R,H,C]
    const void* root2 = d_in[6];  // [H,C]
    const void* b2    = d_in[7];  // [C]

    // ws (u32 words, ~32.3 MB total):
    // copies[8][CW] (x[800000] overlays after scatter) | totals[800000] |
    // rank16[800000 w] | offs[Nn+4] | bsum[256] | carry[256] |
    // segbase[1600000] | sorted[Ee] | flag[1]
    unsigned* copies = (unsigned*)d_ws;
    unsigned* totals = copies + (size_t)NXCD * CW;
    unsigned short* rank16 = (unsigned short*)(totals + (size_t)Nn * 16);
    int* offs  = (int*)(rank16 + Ee);
    int* bsum  = offs + Nn + 4;
    int* carry = bsum + 256;
    unsigned* segbase = (unsigned*)(carry + 256);
    unsigned* sorted  = segbase + (size_t)Nn * 32;
    int* flag  = (int*)(sorted + Ee);
    float* x   = (float*)copies;     // overlay: copies dead after scatter

    hipMemsetAsync(copies, 0, (size_t)NXCD * CW * sizeof(unsigned), stream);

    sniff_kernel<<<1, 64, 0, stream>>>((const unsigned short*)w1, flag);
    count_kernel<<<(Ee + 256 * KC - 1) / (256 * KC), 256, 0, stream>>>(dst, et, copies, rank16);
    merge_kernel<<<(CW + 255) / 256, 256, 0, stream>>>(copies, (uint2*)totals);
    scan1_kernel<<<NBLK, 256, 0, stream>>>((const uint4*)totals, offs, bsum);
    scan2_kernel<<<1, 256, 0, stream>>>(bsum, carry, offs);
    scan3_kernel<<<NBLK, 256, 0, stream>>>(offs, carry);
    segbase_kernel<<<Nn / 8, 256, 0, stream>>>(offs, totals, segbase);
    scatter_kernel<<<(Ee + 256 * KS - 1) / (256 * KS), 256, 0, stream>>>(src, dst, et, segbase,
                                                                        copies, rank16, sorted);
    l1_kernel<<<Nn / 4, 256, 0, stream>>>(sorted, offs, w1, root1, b1, flag, x);
    l2_kernel<<<Nn / 4, 256, 0, stream>>>(sorted, offs, x, w2, root2, b2, flag, d_out);
}

// Round 4
// 306.696 us; speedup vs baseline: 1.2649x; 1.2501x over previous
//
#include <hip/hip_runtime.h>
#include <hip/hip_bf16.h>

// RGCN 2-layer forward. Round-4 pivot: rounds 0-3 proved a hard memory-side
// atomic ceiling (~23 Gatomic/s, 32B write-through per op, invariant across
// scope/layout/MLP) — so the per-edge global-atomic counting sort is floored
// at ~65us. Replaced with a two-level LDS-histogram radix sort (zero global
// atomics): histA (coarse bucket dst>>7 histogram) -> scanB1/B2 (bucket-major
// scan) -> scatC (coarse scatter, LDS ranks) -> sortD (per-bucket 128x32-cell
// LDS counting sort; emits final sorted words + offs directly).
// l1/l2 unchanged: sorted word = src | rel<<16 | min(cnt,2047)<<21.

constexpr int Nn = 50000;
constexpr int Hh = 16;
constexpr int Rr = 32;
constexpr int Cc = 8;
constexpr int Ee = 1600000;
constexpr int CHUNK = 4096;                    // edges per chunk (histA/scatC block)
constexpr int NC = (Ee + CHUNK - 1) / CHUNK;   // 391 chunks
constexpr int DSH = 7;                         // bucket = dst >> 7 (128 dsts/bucket)
constexpr unsigned DLOWM = 127u;
constexpr int NBKT = (Nn + 127) / 128;         // 391 buckets

__device__ __forceinline__ float b2f(__hip_bfloat16 v) { return __bfloat162float(v); }

// --- 0. dtype sniff (bf16 vs fp32 delivery) -----------------------------------
__global__ void sniff_kernel(const unsigned short* __restrict__ w, int* __restrict__ flag) {
    if (blockIdx.x == 0 && threadIdx.x == 0) {
        int hits = 0;
        for (int i = 0; i < 64; ++i) {
            unsigned short u = w[2 * i];
            int e = (u >> 7) & 0xFF;
            if (e >= 100 && e <= 130) ++hits;
        }
        *flag = (hits >= 32) ? 1 : 0;   // 1 = bf16, 0 = fp32
    }
}

// --- 1. coarse histogram: H[chunk][bucket], LDS atomics only ------------------
__global__ __launch_bounds__(256) void histA_kernel(const int* __restrict__ dst,
                                                    unsigned* __restrict__ H) {
    __shared__ unsigned hb[NBKT];
    int c = blockIdx.x, tid = threadIdx.x;
    for (int i = tid; i < NBKT; i += 256) hb[i] = 0;
    __syncthreads();
    int base = c * CHUNK;
    int n = min(CHUNK, Ee - base);
    for (int i = tid; i < n; i += 256)
        atomicAdd(&hb[((unsigned)dst[base + i]) >> DSH], 1u);
    __syncthreads();
    for (int i = tid; i < NBKT; i += 256) H[(size_t)c * NBKT + i] = hb[i];
}

// --- 2a. per-bucket scan over chunks: cb[b][c] = exclusive within bucket ------
__global__ __launch_bounds__(256) void scanB1_kernel(const unsigned* __restrict__ H,
                                                     unsigned* __restrict__ cb,
                                                     unsigned* __restrict__ bt) {
    __shared__ int lsum[4];
    int b = blockIdx.x, t = threadIdx.x, lane = t & 63, wv = t >> 6;
    int c0 = 2 * t, c1 = 2 * t + 1;
    int v0 = (c0 < NC) ? (int)H[(size_t)c0 * NBKT + b] : 0;
    int v1 = (c1 < NC) ? (int)H[(size_t)c1 * NBKT + b] : 0;
    int pair = v0 + v1, s = pair;
#pragma unroll
    for (int o = 1; o < 64; o <<= 1) { int u = __shfl_up(s, o, 64); if (lane >= o) s += u; }
    if (lane == 63) lsum[wv] = s;
    __syncthreads();
    int basev = 0;
    for (int j = 0; j < wv; ++j) basev += lsum[j];
    int incl = basev + s, eoff = incl - pair;
    if (c0 < NC) cb[(size_t)b * NC + c0] = (unsigned)eoff;
    if (c1 < NC) cb[(size_t)b * NC + c1] = (unsigned)(eoff + v0);
    if (t == 255) bt[b] = (unsigned)incl;
}

// --- 2b. scan bucket totals -> rbase[b] (exclusive); rbase[NBKT] = Ee ---------
__global__ __launch_bounds__(256) void scanB2_kernel(const unsigned* __restrict__ bt,
                                                     unsigned* __restrict__ rbase) {
    __shared__ int lsum[4];
    int t = threadIdx.x, lane = t & 63, wv = t >> 6;
    int c0 = 2 * t, c1 = 2 * t + 1;
    int v0 = (c0 < NBKT) ? (int)bt[c0] : 0;
    int v1 = (c1 < NBKT) ? (int)bt[c1] : 0;
    int pair = v0 + v1, s = pair;
#pragma unroll
    for (int o = 1; o < 64; o <<= 1) { int u = __shfl_up(s, o, 64); if (lane >= o) s += u; }
    if (lane == 63) lsum[wv] = s;
    __syncthreads();
    int basev = 0;
    for (int j = 0; j < wv; ++j) basev += lsum[j];
    int incl = basev + s, eoff = incl - pair;
    if (c0 < NBKT) rbase[c0] = (unsigned)eoff;
    if (c1 < NBKT) rbase[c1] = (unsigned)(eoff + v0);
    if (t == 255) rbase[NBKT] = (unsigned)incl;   // == Ee
}

// --- 3. coarse scatter into bucket regions; LDS ranks, zero global atomics ----
__global__ __launch_bounds__(256) void scatC_kernel(const int* __restrict__ src,
                                                    const int* __restrict__ dst,
                                                    const int* __restrict__ et,
                                                    const unsigned* __restrict__ cb,
                                                    const unsigned* __restrict__ rbase,
                                                    unsigned* __restrict__ rec) {
    __shared__ unsigned cbl[NBKT];
    __shared__ unsigned hb[NBKT];
    int c = blockIdx.x, tid = threadIdx.x;
    for (int i = tid; i < NBKT; i += 256) {
        cbl[i] = cb[(size_t)i * NC + c] + rbase[i];
        hb[i] = 0;
    }
    __syncthreads();
    int base = c * CHUNK;
    int n = min(CHUNK, Ee - base);
    for (int i = tid; i < n; i += 256) {
        int e = base + i;
        unsigned d = (unsigned)dst[e];
        unsigned r = (unsigned)et[e];
        unsigned sv = (unsigned)src[e];
        unsigned bkt = d >> DSH;
        unsigned rank = atomicAdd(&hb[bkt], 1u);
        unsigned pos = cbl[bkt] + rank;
        rec[pos] = sv | (r << 16) | ((d & DLOWM) << 21);   // src16 | rel5 | dlow7
    }
}

// --- 4. per-bucket counting sort: 128 dst x 32 rel cells in LDS ---------------
// pass1 count -> per-dst seq scan (stride-33, bank-conflict-free) + 128-wide
// block scan -> offs[] write -> pass2 place with baked min(cnt,2047).
__global__ __launch_bounds__(256) void sortD_kernel(const unsigned* __restrict__ rec,
                                                    const unsigned* __restrict__ rbase,
                                                    unsigned* __restrict__ sorted,
                                                    int* __restrict__ offs) {
    __shared__ unsigned cnt[128 * 33];
    __shared__ unsigned sbase[128 * 33];
    __shared__ int l2s[2];
    int b = blockIdx.x, t = threadIdx.x, lane = t & 63, wv = t >> 6;
    for (int i = t; i < 128 * 33; i += 256) { cnt[i] = 0; sbase[i] = 0; }
    __syncthreads();
    unsigned rb = rbase[b];
    unsigned re = (b == NBKT - 1) ? (unsigned)Ee : rbase[b + 1];
    int n = (int)(re - rb);
    for (int i = t; i < n; i += 256) {
        unsigned w = rec[rb + i];
        atomicAdd(&cnt[((w >> 21) & 127u) * 33 + ((w >> 16) & 31u)], 1u);
    }
    __syncthreads();
    int deg = 0;
    if (t < 128) {
#pragma unroll
        for (int r = 0; r < 32; ++r) {
            unsigned cc = cnt[t * 33 + r];
            sbase[t * 33 + r] = (unsigned)deg;
            deg += (int)cc;
        }
    }
    int s = deg;
#pragma unroll
    for (int o = 1; o < 64; o <<= 1) { int u = __shfl_up(s, o, 64); if (lane >= o) s += u; }
    if (lane == 63 && wv < 2) l2s[wv] = s;
    __syncthreads();
    if (t < 128) {
        int excl = s - deg + (wv == 1 ? l2s[0] : 0);
        unsigned ab = rb + (unsigned)excl;
        int d = b * 128 + t;
        if (d <= Nn) offs[d] = (int)ab;   // d==Nn (b=390,t=80) -> offs[Nn]=Ee
#pragma unroll
        for (int r = 0; r < 32; ++r) sbase[t * 33 + r] += ab;
    }
    __syncthreads();
    for (int i = t; i < n; i += 256) {
        unsigned w = rec[rb + i];
        unsigned dlow = (w >> 21) & 127u, rel = (w >> 16) & 31u, sv = w & 0xFFFFu;
        int cell = (int)dlow * 33 + (int)rel;
        unsigned pos = atomicAdd(&sbase[cell], 1u);
        unsigned cc = cnt[cell];
        if (cc > 2047u) cc = 2047u;
        sorted[pos] = sv | (rel << 16) | (cc << 21);
    }
}

// --- 5. layer 1: one wave per dst, 8 edges x 8 lanes (bf16x2/float2) ----------
__global__ __launch_bounds__(256) void l1_kernel(const unsigned* __restrict__ sorted,
                                                 const int* __restrict__ offs,
                                                 const void* __restrict__ w1,
                                                 const void* __restrict__ root1,
                                                 const void* __restrict__ b1,
                                                 const int* __restrict__ flag,
                                                 float* __restrict__ x) {
    int tid = threadIdx.x, w = tid >> 6, lane = tid & 63;
    int ep = lane >> 3, hp = lane & 7;
    int isbf = *flag;
    int d = blockIdx.x * 4 + w;                  // 12500*4 == Nn
    int off = offs[d], deg = offs[d + 1] - off;
    float a0 = 0.0f, a1 = 0.0f;
    if (isbf) {
#pragma unroll 2
        for (int i = ep; i < deg; i += 8) {
            unsigned p = sorted[off + i];
            int cnt = p >> 21, rel = (p >> 16) & 31, s = p & 0xFFFF;
            float inv = __builtin_amdgcn_rcpf((float)cnt);
            __hip_bfloat162 v = ((const __hip_bfloat162*)w1)[((size_t)rel * Nn + s) * 8 + hp];
            a0 += inv * __low2float(v); a1 += inv * __high2float(v);
        }
    } else {
#pragma unroll 2
        for (int i = ep; i < deg; i += 8) {
            unsigned p = sorted[off + i];
            int cnt = p >> 21, rel = (p >> 16) & 31, s = p & 0xFFFF;
            float inv = __builtin_amdgcn_rcpf((float)cnt);
            float2 v = ((const float2*)w1)[((size_t)rel * Nn + s) * 8 + hp];
            a0 += inv * v.x; a1 += inv * v.y;
        }
    }
#pragma unroll
    for (int o = 8; o < 64; o <<= 1) {
        a0 += __shfl_xor(a0, o, 64);
        a1 += __shfl_xor(a1, o, 64);
    }
    if (ep == 0) {
        float r0, r1v, bb0, bb1;
        if (isbf) {
            r0  = b2f(((const __hip_bfloat16*)root1)[d * Hh + hp * 2]);
            r1v = b2f(((const __hip_bfloat16*)root1)[d * Hh + hp * 2 + 1]);
            bb0 = b2f(((const __hip_bfloat16*)b1)[hp * 2]);
            bb1 = b2f(((const __hip_bfloat16*)b1)[hp * 2 + 1]);
        } else {
            r0  = ((const float*)root1)[d * Hh + hp * 2];
            r1v = ((const float*)root1)[d * Hh + hp * 2 + 1];
            bb0 = ((const float*)b1)[hp * 2];
            bb1 = ((const float*)b1)[hp * 2 + 1];
        }
        float v0 = a0 + r0 + bb0, v1 = a1 + r1v + bb1;
        *(float2*)(x + (size_t)d * Hh + hp * 2) =
            make_float2(v0 > 0.f ? v0 : 0.f, v1 > 0.f ? v1 : 0.f);
    }
}

// --- 6. layer 2 + epilogue: one wave per dst, 8 edges x 8 classes, reg dots ---
__global__ __launch_bounds__(256) void l2_kernel(const unsigned* __restrict__ sorted,
                                                 const int* __restrict__ offs,
                                                 const float* __restrict__ x,
                                                 const void* __restrict__ w2,
                                                 const void* __restrict__ root2,
                                                 const void* __restrict__ b2v,
                                                 const int* __restrict__ flag,
                                                 void* __restrict__ out) {
    __shared__ float w2s[32 * 132];   // [rel]*132 + c*16 + h  (pad 132: ~2-way banks)
    __shared__ float rsh[128];        // root2 [h*8+c]
    __shared__ float b2sh[8];
    int tid = threadIdx.x, w = tid >> 6, lane = tid & 63;
    int isbf = *flag;
    {
        int r = tid >> 3, cc = tid & 7;
        if (isbf) {
            const __hip_bfloat16* W = (const __hip_bfloat16*)w2 + r * 128 + cc;
#pragma unroll
            for (int h = 0; h < 16; ++h) w2s[r * 132 + cc * 16 + h] = b2f(W[h * 8]);
        } else {
            const float* W = (const float*)w2 + r * 128 + cc;
#pragma unroll
            for (int h = 0; h < 16; ++h) w2s[r * 132 + cc * 16 + h] = W[h * 8];
        }
    }
    if (tid < 128) rsh[tid] = isbf ? b2f(((const __hip_bfloat16*)root2)[tid])
                                   : ((const float*)root2)[tid];
    if (tid < 8)   b2sh[tid] = isbf ? b2f(((const __hip_bfloat16*)b2v)[tid])
                                    : ((const float*)b2v)[tid];
    __syncthreads();
    int ep = lane >> 3, c = lane & 7;
    int d = blockIdx.x * 4 + w;
    int off = offs[d], deg = offs[d + 1] - off;
    float acc = 0.0f;
    for (int i0 = 0; i0 < deg; i0 += 8) {
        int i = i0 + ep;
        if (i < deg) {
            unsigned p = sorted[off + i];
            int cnt = p >> 21, rel = (p >> 16) & 31, s = p & 0xFFFF;
            float inv = __builtin_amdgcn_rcpf((float)cnt);
            const float4* xr = (const float4*)(x + (size_t)s * Hh);
            float4 x0 = xr[0], x1 = xr[1], x2 = xr[2], x3 = xr[3];
            const float4* wv = (const float4*)(w2s + rel * 132 + c * 16);
            float4 w0 = wv[0], w1v = wv[1], w2v = wv[2], w3 = wv[3];
            float dot = x0.x*w0.x + x0.y*w0.y + x0.z*w0.z + x0.w*w0.w
                      + x1.x*w1v.x + x1.y*w1v.y + x1.z*w1v.z + x1.w*w1v.w
                      + x2.x*w2v.x + x2.y*w2v.y + x2.z*w2v.z + x2.w*w2v.w
                      + x3.x*w3.x + x3.y*w3.y + x3.z*w3.z + x3.w*w3.w;
            acc += inv * dot;
        }
    }
    acc += __shfl_xor(acc, 8, 64);
    acc += __shfl_xor(acc, 16, 64);
    acc += __shfl_xor(acc, 32, 64);
    if (ep == 0) {
        const float4* xr = (const float4*)(x + (size_t)d * Hh);
        float4 x0 = xr[0], x1 = xr[1], x2 = xr[2], x3 = xr[3];
        float xv[16] = {x0.x,x0.y,x0.z,x0.w, x1.x,x1.y,x1.z,x1.w,
                        x2.x,x2.y,x2.z,x2.w, x3.x,x3.y,x3.z,x3.w};
        float v = acc + b2sh[c];
#pragma unroll
        for (int h = 0; h < 16; ++h) v += xv[h] * rsh[h * 8 + c];
        float m = v;
#pragma unroll
        for (int o = 1; o < 8; o <<= 1) m = fmaxf(m, __shfl_xor(m, o, 8));
        float ssum = __expf(v - m);
#pragma unroll
        for (int o = 1; o < 8; o <<= 1) ssum += __shfl_xor(ssum, o, 8);
        float res = v - m - __logf(ssum);
        if (isbf) ((__hip_bfloat16*)out)[(size_t)d * Cc + c] = __float2bfloat16(res);
        else      ((float*)out)[(size_t)d * Cc + c] = res;
    }
}

extern "C" void kernel_launch(void* const* d_in, const int* in_sizes, int n_in,
                              void* d_out, int out_size, void* d_ws, size_t ws_size,
                              hipStream_t stream) {
    const int* edge_index = (const int*)d_in[0];     // [2, E]
    const int* src = edge_index;
    const int* dst = edge_index + Ee;
    const int* et  = (const int*)d_in[1];            // [E]
    const void* w1    = d_in[2];  // [R,N,H]
    const void* root1 = d_in[3];  // [N,H]
    const void* b1    = d_in[4];  // [H]
    const void* w2    = d_in[5];  // [R,H,C]
    const void* root2 = d_in[6];  // [H,C]
    const void* b2    = d_in[7];  // [C]

    // ws (u32 words, ~14.2 MB): rec[Ee] (x[800000] overlays after sortD) |
    // sorted[Ee] | H[NC*NBKT] | cb[NBKT*NC] | bt[NBKT] | rbase[NBKT+1] |
    // offs[Nn+1] | flag[1].  No global memset needed: every word is
    // fully written before read.
    unsigned* rec    = (unsigned*)d_ws;
    unsigned* sorted = rec + Ee;
    unsigned* H      = sorted + Ee;
    unsigned* cb     = H + (size_t)NC * NBKT;
    unsigned* bt     = cb + (size_t)NBKT * NC;
    unsigned* rbase  = bt + NBKT;
    int* offs        = (int*)(rbase + NBKT + 1);
    int* flag        = offs + Nn + 1;
    float* x         = (float*)rec;    // overlay: rec dead after sortD

    sniff_kernel<<<1, 64, 0, stream>>>((const unsigned short*)w1, flag);
    histA_kernel<<<NC, 256, 0, stream>>>(dst, H);
    scanB1_kernel<<<NBKT, 256, 0, stream>>>(H, cb, bt);
    scanB2_kernel<<<1, 256, 0, stream>>>(bt, rbase);
    scatC_kernel<<<NC, 256, 0, stream>>>(src, dst, et, cb, rbase, rec);
    sortD_kernel<<<NBKT, 256, 0, stream>>>(rec, rbase, sorted, offs);
    l1_kernel<<<Nn / 4, 256, 0, stream>>>(sorted, offs, w1, root1, b1, flag, x);
    l2_kernel<<<Nn / 4, 256, 0, stream>>>(sorted, offs, x, w2, root2, b2, flag, d_out);
}